// Round 12
// baseline (2061.660 us; speedup 1.0000x reference)
//
#include <hip/hip_runtime.h>
#include <hip/hip_fp16.h>

#define NN 100000
#define NE 1600000
#define CH 64
#define STEPS 10
#define ALPHA 0.1f
#define NG 8                         // channel groups (one per XCD)

#define BW 256                       // nodes per bucket
#define NB ((NN + BW - 1) / BW)      // 391 buckets
#define PBLK 256                     // partition blocks
#define PCHUNK (NE / PBLK)           // 6250 edges per partition block

typedef unsigned int uint;
typedef unsigned long long ull;

// pack two f32 into bf16x2 word, RNE (low half = first arg)
__device__ inline uint pack_bf16x2(float x, float y) {
    uint ux = __float_as_uint(x);
    ux += 0x7FFFu + ((ux >> 16) & 1u);
    uint uy = __float_as_uint(y);
    uy += 0x7FFFu + ((uy >> 16) & 1u);
    return (ux >> 16) | (uy & 0xFFFF0000u);
}

// ---- phase 1: per-block LDS bucket histogram -> dense histAll write ----
__global__ __launch_bounds__(256) void
k_hist(const int* __restrict__ dst, int* __restrict__ histAll) {
    __shared__ int hist[NB];
    int tid = threadIdx.x;
    for (int i = tid; i < NB; i += 256) hist[i] = 0;
    __syncthreads();
    int s0 = blockIdx.x * PCHUNK;
    for (int i = s0 + tid; i < s0 + PCHUNK; i += 256)
        atomicAdd(&hist[dst[i] >> 8], 1);
    __syncthreads();
    for (int b = tid; b < NB; b += 256)
        histAll[blockIdx.x * NB + b] = hist[b];
}

// ---- phase 2a: per-bucket scan over blocks ----
__global__ __launch_bounds__(256) void
k_colscan(int* __restrict__ histAll, int* __restrict__ bcnt) {
    __shared__ int lds[256];
    int b = blockIdx.x, tid = threadIdx.x;
    int v = histAll[tid * NB + b];
    lds[tid] = v;
    __syncthreads();
    for (int off = 1; off < 256; off <<= 1) {
        int t = (tid >= off) ? lds[tid - off] : 0;
        __syncthreads();
        lds[tid] += t;
        __syncthreads();
    }
    histAll[tid * NB + b] = lds[tid] - v;
    if (tid == 255) bcnt[b] = lds[255];
}

// ---- phase 2b: exclusive scan of 391 bucket sums ----
__global__ void k_scanb(const int* __restrict__ bcnt, int* __restrict__ bbase) {
    __shared__ int lds[512];
    int tid = threadIdx.x;
    int v = (tid < NB) ? bcnt[tid] : 0;
    lds[tid] = v;
    __syncthreads();
    for (int off = 1; off < 512; off <<= 1) {
        int t = (tid >= off) ? lds[tid - off] : 0;
        __syncthreads();
        lds[tid] += t;
        __syncthreads();
    }
    if (tid < NB) bbase[tid] = lds[tid] - v;
    if (tid == 0) bbase[NB] = NE;
}

// ---- phase 3: scatter 4B (src | dl<<17) into reserved dense runs ----
__global__ __launch_bounds__(256) void
k_partA2(const int* __restrict__ src, const int* __restrict__ dst,
         const int* __restrict__ histAll, const int* __restrict__ bbase,
         uint* __restrict__ tmp) {
    __shared__ int gb[NB];
    __shared__ int lcur[NB];
    int tid = threadIdx.x;
    for (int b = tid; b < NB; b += 256) {
        gb[b] = bbase[b] + histAll[blockIdx.x * NB + b];
        lcur[b] = 0;
    }
    __syncthreads();
    int s0 = blockIdx.x * PCHUNK;
    for (int i = s0 + tid; i < s0 + PCHUNK; i += 256) {
        int d = dst[i];
        int b = d >> 8;
        int r = atomicAdd(&lcur[b], 1);
        tmp[gb[b] + r] = (uint)src[i] | ((uint)(d & 255) << 17);
    }
}

// ---- phase 4: per-bucket degree histogram -> dinv + rowptr ----
__global__ __launch_bounds__(256) void
k_partB1(const uint* __restrict__ tmp, const int* __restrict__ bbase,
         float* __restrict__ dinv, int* __restrict__ rowptr) {
    __shared__ int hist[256];
    __shared__ int lds[256];
    int b = blockIdx.x, tid = threadIdx.x;
    int nb0 = b * BW;
    int nodes = (NN - nb0 < BW) ? (NN - nb0) : BW;
    int base = bbase[b];
    int m = bbase[b + 1] - base;
    hist[tid] = 0;
    __syncthreads();
    for (int i = tid; i < m; i += 256)
        atomicAdd(&hist[(tmp[base + i] >> 17) & 255], 1);
    __syncthreads();
    int v = hist[tid];
    lds[tid] = v;
    __syncthreads();
    for (int off = 1; off < 256; off <<= 1) {
        int t = (tid >= off) ? lds[tid - off] : 0;
        __syncthreads();
        lds[tid] += t;
        __syncthreads();
    }
    if (tid < nodes) {
        dinv[nb0 + tid] = rsqrtf(fmaxf((float)v, 1.0f));
        rowptr[nb0 + tid] = base + lds[tid] - v;
    }
    if (b == 0 && tid == 0) rowptr[NN] = NE;
}

// ---- phase 5: per-bucket sort-by-dst -> 4B rec = src | (f16(w)>>1)<<17 ----
__global__ __launch_bounds__(256) void
k_partB2(const uint* __restrict__ tmp, const int* __restrict__ bbase,
         const float* __restrict__ dinv, uint* __restrict__ rec) {
    __shared__ int hist[256];
    __shared__ int lds[256];
    __shared__ int lcur[256];
    int b = blockIdx.x, tid = threadIdx.x;
    int nb0 = b * BW;
    int base = bbase[b];
    int m = bbase[b + 1] - base;
    hist[tid] = 0;
    __syncthreads();
    for (int i = tid; i < m; i += 256)
        atomicAdd(&hist[(tmp[base + i] >> 17) & 255], 1);
    __syncthreads();
    int v = hist[tid];
    lds[tid] = v;
    __syncthreads();
    for (int off = 1; off < 256; off <<= 1) {
        int t = (tid >= off) ? lds[tid - off] : 0;
        __syncthreads();
        lds[tid] += t;
        __syncthreads();
    }
    lcur[tid] = lds[tid] - v;
    __syncthreads();
    for (int i = tid; i < m; i += 256) {
        uint r = tmp[base + i];
        int dl = (r >> 17) & 255;
        int sv = (int)(r & 0x1FFFFu);
        float w = dinv[sv] * dinv[nb0 + dl];
        unsigned short hw = __half_as_ushort(__float2half_rn(w));
        int p = atomicAdd(&lcur[dl], 1);
        rec[base + p] = (uint)sv | ((uint)(hw >> 1) << 17);
    }
}

// ---- transpose x (f32 [node][64]) -> xq (bf16 grouped [g][node][16B]) ----
__global__ __launch_bounds__(256) void
k_xq(const float* __restrict__ x, uint* __restrict__ xq) {
    int i = blockIdx.x * 256 + threadIdx.x;     // [0, NN*32)
    int node = i >> 5, ju = i & 31;             // ju = uint index in 64-ch row
    float2 v = ((const float2*)x)[(size_t)node * 32 + ju];
    int g = ju >> 2, c = ju & 3;
    xq[((size_t)g * NN + node) * 4 + c] = pack_bf16x2(v.x, v.y);
}

// ---- propagation, grouped: g = blockIdx&7 -> XCD-resident 1.6MB slice.
//      One wave per (node, group): 32 edge slots x 2 lanes (uint2 = 4 ch).
//      One NT record load (32 recs = 128B) + one gather covers deg<=32. ----
__global__ __launch_bounds__(1024) void
k_prop(const int* __restrict__ rowptr, const uint* __restrict__ rec,
       const uint* __restrict__ hsrc, uint* __restrict__ hdst) {
    int g    = blockIdx.x & 7;
    int node = (blockIdx.x >> 3) * 16 + (threadIdx.x >> 6);
    int lane = threadIdx.x & 63;
    int e = lane >> 1;               // edge slot [0,32)
    int c = lane & 1;                // uint2 slot (4 channels)
    int start = rowptr[node];
    int end   = rowptr[node + 1];
    int safe  = start < NE ? start : NE - 1;
    const uint2* __restrict__ hg = (const uint2*)(hsrc + (size_t)g * (NN * 4));

    float a0 = 0.f, a1 = 0.f, a2 = 0.f, a3 = 0.f;

    #define EDGE(IX, ACTIVE, NT)                                                  \
        {                                                                         \
            uint r_ = (NT) ? __builtin_nontemporal_load(rec + (IX))               \
                           : rec[(IX)];                                           \
            int  s_ = (int)(r_ & 0x1FFFFu);                                       \
            uint2 hv = hg[(size_t)s_ * 2 + c];                                    \
            float wt = (ACTIVE)                                                   \
                ? __half2float(__ushort_as_half((unsigned short)((r_ >> 17) << 1)))\
                : 0.0f;                                                           \
            a0 = fmaf(__uint_as_float(hv.x << 16),         wt, a0);               \
            a1 = fmaf(__uint_as_float(hv.x & 0xFFFF0000u), wt, a1);               \
            a2 = fmaf(__uint_as_float(hv.y << 16),         wt, a2);               \
            a3 = fmaf(__uint_as_float(hv.y & 0xFFFF0000u), wt, a3);               \
        }

    {   // main batch: 32 edges in one shot
        int ix = start + e;
        EDGE(ix < end ? ix : safe, ix < end, true);
    }
    // rare tail: deg > 32
    for (int p0 = start + 32; p0 < end; p0 += 32) {
        int ix = p0 + e;
        if (ix < end) EDGE(ix, true, true);
    }
    #undef EDGE

    // reduce across 32 edge slots (lane bits 1..5)
    a0 += __shfl_xor(a0, 2);  a1 += __shfl_xor(a1, 2);
    a2 += __shfl_xor(a2, 2);  a3 += __shfl_xor(a3, 2);
    a0 += __shfl_xor(a0, 4);  a1 += __shfl_xor(a1, 4);
    a2 += __shfl_xor(a2, 4);  a3 += __shfl_xor(a3, 4);
    a0 += __shfl_xor(a0, 8);  a1 += __shfl_xor(a1, 8);
    a2 += __shfl_xor(a2, 8);  a3 += __shfl_xor(a3, 8);
    a0 += __shfl_xor(a0, 16); a1 += __shfl_xor(a1, 16);
    a2 += __shfl_xor(a2, 16); a3 += __shfl_xor(a3, 16);
    a0 += __shfl_xor(a0, 32); a1 += __shfl_xor(a1, 32);
    a2 += __shfl_xor(a2, 32); a3 += __shfl_xor(a3, 32);

    if (e == 0) {   // lanes 0,1 write uint2 each -> 16B row
        uint2* __restrict__ hd = (uint2*)(hdst + (size_t)g * (NN * 4));
        hd[(size_t)node * 2 + c] = make_uint2(pack_bf16x2(a0, a1), pack_bf16x2(a2, a3));
    }
}

// ---- final: out = alpha*x + (1-alpha)/STEPS * sum_t h_t (LDS transpose) ----
__global__ __launch_bounds__(256) void
k_sum10(const uint* __restrict__ hbase, const float* __restrict__ x,
        float* __restrict__ out) {
    __shared__ float lds[32][65];
    int tid = threadIdx.x;
    int g = tid & 7, nl = tid >> 3;          // 32 nodes x 8 groups
    int node = blockIdx.x * 32 + nl;
    float s0=0,s1=0,s2=0,s3=0,s4=0,s5=0,s6=0,s7=0;
    #pragma unroll
    for (int t = 0; t < STEPS; ++t) {
        const uint4* b = (const uint4*)(hbase + (size_t)t * (NG * NN * 4));
        uint4 v = b[(size_t)g * NN + node];
        s0 += __uint_as_float(v.x << 16); s1 += __uint_as_float(v.x & 0xFFFF0000u);
        s2 += __uint_as_float(v.y << 16); s3 += __uint_as_float(v.y & 0xFFFF0000u);
        s4 += __uint_as_float(v.z << 16); s5 += __uint_as_float(v.z & 0xFFFF0000u);
        s6 += __uint_as_float(v.w << 16); s7 += __uint_as_float(v.w & 0xFFFF0000u);
    }
    const float k = (1.0f - ALPHA) * (1.0f / STEPS);
    lds[nl][g*8+0] = s0*k; lds[nl][g*8+1] = s1*k;
    lds[nl][g*8+2] = s2*k; lds[nl][g*8+3] = s3*k;
    lds[nl][g*8+4] = s4*k; lds[nl][g*8+5] = s5*k;
    lds[nl][g*8+6] = s6*k; lds[nl][g*8+7] = s7*k;
    __syncthreads();
    #pragma unroll
    for (int it = 0; it < 2; ++it) {
        int idx = it * 256 + tid;            // [0,512): 32 nodes x 16 float4
        int nl2 = idx >> 4, q = idx & 15;
        float4 xv = ((const float4*)x)[((size_t)blockIdx.x * 32 + nl2) * 16 + q];
        float4 r;
        r.x = ALPHA * xv.x + lds[nl2][q*4+0];
        r.y = ALPHA * xv.y + lds[nl2][q*4+1];
        r.z = ALPHA * xv.z + lds[nl2][q*4+2];
        r.w = ALPHA * xv.w + lds[nl2][q*4+3];
        ((float4*)out)[((size_t)blockIdx.x * 32 + nl2) * 16 + q] = r;
    }
}

extern "C" void kernel_launch(void* const* d_in, const int* in_sizes, int n_in,
                              void* d_out, int out_size, void* d_ws, size_t ws_size,
                              hipStream_t stream) {
    const float* x  = (const float*)d_in[0];
    const int*   ei = (const int*)d_in[1];     // [2, NE]: row0=src, row1=dst
    const int*   src = ei;
    const int*   dst = ei + NE;
    float* out = (float*)d_out;

    char* ws = (char*)d_ws;
    const size_t MB = 1024 * 1024;
    const size_t KB = 1024;
    int*   histAll = (int*)  (ws);                     // ~400 KB
    float* dinv    = (float*)(ws + 1 * MB);            // 400 KB
    int*   rowptr  = (int*)  (ws + 2 * MB);            // 400 KB (+1)
    int*   bcnt    = (int*)  (ws + 3 * MB);            // ~1.6 KB
    int*   bbase   = (int*)  (ws + 3 * MB + 64 * KB);  // ~1.6 KB (+1)
    uint*  rec     = (uint*) (ws + 5 * MB);            // 6.4 MB (final CSR, 4B recs)
    uint*  hbase   = (uint*) (ws + 20 * MB);           // 10 x 12.8 MB = 128 MB
    uint*  tmp     = (uint*) (ws + 20 * MB);           // 6.4 MB (dead before prop 0)
    uint*  xq      = (uint*) d_out;                    // 12.8 MB; dead by k_sum10

    const size_t GSZ = (size_t)NG * NN * 4;            // uints per time-buffer

    k_hist   <<<PBLK, 256, 0, stream>>>(dst, histAll);
    k_colscan<<<NB, 256, 0, stream>>>(histAll, bcnt);
    k_scanb  <<<1, 512, 0, stream>>>(bcnt, bbase);
    k_partA2 <<<PBLK, 256, 0, stream>>>(src, dst, histAll, bbase, tmp);
    k_partB1 <<<NB, 256, 0, stream>>>(tmp, bbase, dinv, rowptr);
    k_partB2 <<<NB, 256, 0, stream>>>(tmp, bbase, dinv, rec);
    k_xq     <<<(NN * 32) / 256, 256, 0, stream>>>(x, xq);

    const int propBlocks = NG * (NN / 16);             // 50000; g = blockIdx&7
    const uint* hcur = xq;
    for (int t = 0; t < STEPS; ++t) {
        uint* hn = hbase + (size_t)t * GSZ;
        k_prop<<<propBlocks, 1024, 0, stream>>>(rowptr, rec, hcur, hn);
        hcur = hn;
    }

    k_sum10<<<NN / 32, 256, 0, stream>>>(hbase, x, out);
}

// Round 14
// 1318.183 us; speedup vs baseline: 1.5640x; 1.5640x over previous
//
#include <hip/hip_runtime.h>
#include <hip/hip_fp16.h>

#define NN 100000
#define NE 1600000
#define CH 64
#define STEPS 10
#define ALPHA 0.1f
#define NG 4                 // channel groups; group g -> XCDs {g, g+4}
#define GCH 16               // channels per group; row = 32 B

#define BW 256                       // nodes per bucket
#define NB ((NN + BW - 1) / BW)      // 391 buckets
#define PBLK 256                     // partition blocks
#define PCHUNK (NE / PBLK)           // 6250 edges per partition block
#define NDC 65                       // degree classes 0..64 (64 = clamp)

typedef unsigned int uint;
typedef unsigned short ushort;
typedef unsigned long long ull;

// pack two f32 into bf16x2 word, RNE (low half = first arg)
__device__ inline uint pack_bf16x2(float x, float y) {
    uint ux = __float_as_uint(x);
    ux += 0x7FFFu + ((ux >> 16) & 1u);
    uint uy = __float_as_uint(y);
    uy += 0x7FFFu + ((uy >> 16) & 1u);
    return (ux >> 16) | (uy & 0xFFFF0000u);
}

// ---- phase 1: per-block LDS bucket histogram -> dense histAll write ----
__global__ __launch_bounds__(256) void
k_hist(const int* __restrict__ dst, int* __restrict__ histAll) {
    __shared__ int hist[NB];
    int tid = threadIdx.x;
    for (int i = tid; i < NB; i += 256) hist[i] = 0;
    __syncthreads();
    int s0 = blockIdx.x * PCHUNK;
    for (int i = s0 + tid; i < s0 + PCHUNK; i += 256)
        atomicAdd(&hist[dst[i] >> 8], 1);
    __syncthreads();
    for (int b = tid; b < NB; b += 256)
        histAll[blockIdx.x * NB + b] = hist[b];
}

// ---- phase 2a: per-bucket scan over blocks ----
__global__ __launch_bounds__(256) void
k_colscan(int* __restrict__ histAll, int* __restrict__ bcnt) {
    __shared__ int lds[256];
    int b = blockIdx.x, tid = threadIdx.x;
    int v = histAll[tid * NB + b];
    lds[tid] = v;
    __syncthreads();
    for (int off = 1; off < 256; off <<= 1) {
        int t = (tid >= off) ? lds[tid - off] : 0;
        __syncthreads();
        lds[tid] += t;
        __syncthreads();
    }
    histAll[tid * NB + b] = lds[tid] - v;
    if (tid == 255) bcnt[b] = lds[255];
}

// ---- phase 2b: exclusive scan of 391 bucket sums ----
__global__ void k_scanb(const int* __restrict__ bcnt, int* __restrict__ bbase) {
    __shared__ int lds[512];
    int tid = threadIdx.x;
    int v = (tid < NB) ? bcnt[tid] : 0;
    lds[tid] = v;
    __syncthreads();
    for (int off = 1; off < 512; off <<= 1) {
        int t = (tid >= off) ? lds[tid - off] : 0;
        __syncthreads();
        lds[tid] += t;
        __syncthreads();
    }
    if (tid < NB) bbase[tid] = lds[tid] - v;
    if (tid == 0) bbase[NB] = NE;
}

// ---- phase 3: scatter 4B (src | dl<<17) into reserved dense runs ----
__global__ __launch_bounds__(256) void
k_partA2(const int* __restrict__ src, const int* __restrict__ dst,
         const int* __restrict__ histAll, const int* __restrict__ bbase,
         uint* __restrict__ tmp) {
    __shared__ int gb[NB];
    __shared__ int lcur[NB];
    int tid = threadIdx.x;
    for (int b = tid; b < NB; b += 256) {
        gb[b] = bbase[b] + histAll[blockIdx.x * NB + b];
        lcur[b] = 0;
    }
    __syncthreads();
    int s0 = blockIdx.x * PCHUNK;
    for (int i = s0 + tid; i < s0 + PCHUNK; i += 256) {
        int d = dst[i];
        int b = d >> 8;
        int r = atomicAdd(&lcur[b], 1);
        tmp[gb[b] + r] = (uint)src[i] | ((uint)(d & 255) << 17);
    }
}

// ---- phase 4: per-bucket degree histogram -> dinv + deg ----
__global__ __launch_bounds__(256) void
k_partB1(const uint* __restrict__ tmp, const int* __restrict__ bbase,
         float* __restrict__ dinv, int* __restrict__ deg) {
    __shared__ int hist[256];
    int b = blockIdx.x, tid = threadIdx.x;
    int nb0 = b * BW;
    int nodes = (NN - nb0 < BW) ? (NN - nb0) : BW;
    int base = bbase[b];
    int m = bbase[b + 1] - base;
    hist[tid] = 0;
    __syncthreads();
    for (int i = tid; i < m; i += 256)
        atomicAdd(&hist[(tmp[base + i] >> 17) & 255], 1);
    __syncthreads();
    if (tid < nodes) {
        int v = hist[tid];
        deg[nb0 + tid] = v;
        dinv[nb0 + tid] = rsqrtf(fmaxf((float)v, 1.0f));
    }
}

// ---- degree-class histogram ----
__global__ void k_dhist(const int* __restrict__ deg, int* __restrict__ dcnt) {
    int i = blockIdx.x * 256 + threadIdx.x;
    if (i < NN) atomicAdd(&dcnt[min(deg[i], 64)], 1);
}

// ---- scan degree classes: dbase (node base), ebase (edge base), cursors ----
__global__ void k_dscan(const int* __restrict__ dcnt, int* __restrict__ dbase,
                        int* __restrict__ ebase, int* __restrict__ dcur) {
    __shared__ int lc[128], le[128];
    int tid = threadIdx.x;
    int c = (tid < NDC) ? dcnt[tid] : 0;
    lc[tid] = c;
    le[tid] = c * tid;
    __syncthreads();
    for (int off = 1; off < 128; off <<= 1) {
        int tc = (tid >= off) ? lc[tid - off] : 0;
        int te = (tid >= off) ? le[tid - off] : 0;
        __syncthreads();
        lc[tid] += tc; le[tid] += te;
        __syncthreads();
    }
    if (tid < NDC) {
        int db = lc[tid] - c;
        dbase[tid] = db;
        ebase[tid] = le[tid] - c * tid;
        dcur[tid] = db;
        if (tid == NDC - 1) dcur[NDC] = le[tid] - c * tid;  // class-64 edge allocator
    }
}

// ---- assign permuted ids; rowptr2 in closed form; degS ----
__global__ void k_dassign(const int* __restrict__ deg, const int* __restrict__ dbase,
                          const int* __restrict__ ebase, int* __restrict__ dcur,
                          int* __restrict__ perm, int* __restrict__ iperm,
                          int* __restrict__ rowptr2, ushort* __restrict__ degS) {
    int i = blockIdx.x * 256 + threadIdx.x;
    if (i >= NN) return;
    int v = deg[i];
    int d = min(v, 64);
    int nid = atomicAdd(&dcur[d], 1);
    perm[nid] = i;
    iperm[i] = nid;
    int rp;
    if (d < 64) rp = ebase[d] + (nid - dbase[d]) * d;
    else        rp = atomicAdd(&dcur[NDC], v);
    rowptr2[nid] = rp;
    degS[nid] = (ushort)v;
}

// ---- phase 5: emit 4B recs (permuted src | f16w>>1 << 17) at permuted CSR pos ----
__global__ __launch_bounds__(256) void
k_partB2(const uint* __restrict__ tmp, const int* __restrict__ bbase,
         const float* __restrict__ dinv, const int* __restrict__ iperm,
         const int* __restrict__ rowptr2, uint* __restrict__ rec) {
    __shared__ int lcur[256];
    __shared__ int lrp[256];
    int b = blockIdx.x, tid = threadIdx.x;
    int nb0 = b * BW;
    int nodes = (NN - nb0 < BW) ? (NN - nb0) : BW;
    int base = bbase[b];
    int m = bbase[b + 1] - base;
    lcur[tid] = 0;
    if (tid < nodes) lrp[tid] = rowptr2[iperm[nb0 + tid]];
    __syncthreads();
    for (int i = tid; i < m; i += 256) {
        uint r = tmp[base + i];
        int dl = (r >> 17) & 255;
        int sv = (int)(r & 0x1FFFFu);
        float w = dinv[sv] * dinv[nb0 + dl];
        ushort hw = __half_as_ushort(__float2half_rn(w));
        int k = atomicAdd(&lcur[dl], 1);
        rec[lrp[dl] + k] = (uint)iperm[sv] | ((uint)(hw >> 1) << 17);
    }
}

// ---- pack x into grouped/permuted bf16 layout [g][newid][32B] ----
__global__ __launch_bounds__(256) void
k_xq(const float* __restrict__ x, const int* __restrict__ perm, uint* __restrict__ xq) {
    int t = blockIdx.x * 256 + threadIdx.x;
    if (t >= NN * NG) return;
    int newid = t >> 2, g = t & 3;
    int orig = perm[newid];
    const float4* xr = (const float4*)(x + (size_t)orig * CH + g * GCH);
    float4 v0 = xr[0], v1 = xr[1], v2 = xr[2], v3 = xr[3];
    uint4* dp = (uint4*)(xq + ((size_t)g * NN + newid) * 8);
    dp[0] = make_uint4(pack_bf16x2(v0.x, v0.y), pack_bf16x2(v0.z, v0.w),
                       pack_bf16x2(v1.x, v1.y), pack_bf16x2(v1.z, v1.w));
    dp[1] = make_uint4(pack_bf16x2(v2.x, v2.y), pack_bf16x2(v2.z, v2.w),
                       pack_bf16x2(v3.x, v3.y), pack_bf16x2(v3.z, v3.w));
}

// ---- propagation: group g = blockIdx&3 (XCD-resident 3.2MB slice).
//      Wave = 4 equal-degree nodes x 4 edge-slots x 4 ch-lanes (uint2 = 4ch).
//      1024 edge-channels/wave; 2-level reduce; NT rec load + NT h store. ----
__global__ __launch_bounds__(256) void
k_prop(const int* __restrict__ rowptr2, const ushort* __restrict__ degS,
       const uint* __restrict__ rec, const uint* __restrict__ hsrc,
       uint* __restrict__ hdst) {
    int g     = blockIdx.x & 3;
    int chunk = blockIdx.x >> 2;
    int lane  = threadIdx.x & 63;
    int ni    = lane >> 4;               // node within wave [0,4)
    int slot  = (lane >> 2) & 3;         // edge slot [0,4)
    int c     = lane & 3;                // uint2 slot (4 ch) [0,4)
    int node  = chunk * 16 + (threadIdx.x >> 6) * 4 + ni;   // newid
    int start = rowptr2[node];
    int d     = degS[node];
    int end   = start + d;
    int safe  = start < NE ? start : NE - 1;
    const uint2* __restrict__ hg = (const uint2*)hsrc + (size_t)g * (NN * 4);

    float a0 = 0.f, a1 = 0.f, a2 = 0.f, a3 = 0.f;
    int p = start + slot;
    while (__any(p < end)) {
        bool act = p < end;
        uint r = __builtin_nontemporal_load(rec + (act ? p : safe));
        int s = (int)(r & 0x1FFFFu);
        uint2 hv = hg[(size_t)s * 4 + c];
        float wt = act ? __half2float(__ushort_as_half((ushort)((r >> 17) << 1))) : 0.0f;
        a0 = fmaf(__uint_as_float(hv.x << 16),         wt, a0);
        a1 = fmaf(__uint_as_float(hv.x & 0xFFFF0000u), wt, a1);
        a2 = fmaf(__uint_as_float(hv.y << 16),         wt, a2);
        a3 = fmaf(__uint_as_float(hv.y & 0xFFFF0000u), wt, a3);
        p += 4;
    }
    a0 += __shfl_xor(a0, 4); a1 += __shfl_xor(a1, 4);
    a2 += __shfl_xor(a2, 4); a3 += __shfl_xor(a3, 4);
    a0 += __shfl_xor(a0, 8); a1 += __shfl_xor(a1, 8);
    a2 += __shfl_xor(a2, 8); a3 += __shfl_xor(a3, 8);
    if (slot == 0) {
        ull* hd = (ull*)((uint2*)hdst + (size_t)g * (NN * 4));
        ull pack = (ull)pack_bf16x2(a0, a1) | ((ull)pack_bf16x2(a2, a3) << 32);
        __builtin_nontemporal_store(pack, &hd[(size_t)node * 4 + c]);
    }
}

// ---- final: out[perm[newid]] = alpha*x + (1-alpha)/STEPS * sum_t h_t ----
__global__ __launch_bounds__(256) void
k_sum10(const uint* __restrict__ hbase, const float* __restrict__ x,
        const int* __restrict__ perm, float* __restrict__ out) {
    int t = blockIdx.x * 256 + threadIdx.x;
    if (t >= NN * NG) return;
    int newid = t >> 2, g = t & 3;
    float s[16];
    #pragma unroll
    for (int j = 0; j < 16; ++j) s[j] = 0.f;
    #pragma unroll
    for (int st = 0; st < STEPS; ++st) {
        const uint4* b = (const uint4*)(hbase + (size_t)st * ((size_t)NG * NN * 8));
        uint4 v0 = b[((size_t)g * NN + newid) * 2];
        uint4 v1 = b[((size_t)g * NN + newid) * 2 + 1];
        s[0]  += __uint_as_float(v0.x << 16); s[1]  += __uint_as_float(v0.x & 0xFFFF0000u);
        s[2]  += __uint_as_float(v0.y << 16); s[3]  += __uint_as_float(v0.y & 0xFFFF0000u);
        s[4]  += __uint_as_float(v0.z << 16); s[5]  += __uint_as_float(v0.z & 0xFFFF0000u);
        s[6]  += __uint_as_float(v0.w << 16); s[7]  += __uint_as_float(v0.w & 0xFFFF0000u);
        s[8]  += __uint_as_float(v1.x << 16); s[9]  += __uint_as_float(v1.x & 0xFFFF0000u);
        s[10] += __uint_as_float(v1.y << 16); s[11] += __uint_as_float(v1.y & 0xFFFF0000u);
        s[12] += __uint_as_float(v1.z << 16); s[13] += __uint_as_float(v1.z & 0xFFFF0000u);
        s[14] += __uint_as_float(v1.w << 16); s[15] += __uint_as_float(v1.w & 0xFFFF0000u);
    }
    int orig = perm[newid];
    const float4* xr = (const float4*)(x + (size_t)orig * CH + g * GCH);
    float4* orow = (float4*)(out + (size_t)orig * CH + g * GCH);
    const float k = (1.0f - ALPHA) * (1.0f / STEPS);
    #pragma unroll
    for (int q = 0; q < 4; ++q) {
        float4 xv = xr[q];
        float4 r;
        r.x = ALPHA * xv.x + k * s[q * 4 + 0];
        r.y = ALPHA * xv.y + k * s[q * 4 + 1];
        r.z = ALPHA * xv.z + k * s[q * 4 + 2];
        r.w = ALPHA * xv.w + k * s[q * 4 + 3];
        orow[q] = r;
    }
}

extern "C" void kernel_launch(void* const* d_in, const int* in_sizes, int n_in,
                              void* d_out, int out_size, void* d_ws, size_t ws_size,
                              hipStream_t stream) {
    const float* x  = (const float*)d_in[0];
    const int*   ei = (const int*)d_in[1];     // [2, NE]: row0=src, row1=dst
    const int*   src = ei;
    const int*   dst = ei + NE;
    float* out = (float*)d_out;

    char* ws = (char*)d_ws;
    const size_t MB = 1024 * 1024;
    const size_t KB = 1024;
    int*    histAll = (int*)   (ws);                      // ~400 KB
    float*  dinv    = (float*) (ws + 1 * MB);             // 400 KB
    int*    deg     = (int*)   (ws + 2 * MB);             // 400 KB
    int*    bcnt    = (int*)   (ws + 3 * MB);             // tiny
    int*    bbase   = (int*)   (ws + 3 * MB + 64 * KB);   // tiny (+1)
    int*    dcnt    = (int*)   (ws + 3 * MB + 128 * KB);  // 65 ints
    int*    dbase   = (int*)   (ws + 3 * MB + 192 * KB);  // 65 ints
    int*    ebase   = (int*)   (ws + 3 * MB + 256 * KB);  // 65 ints
    int*    dcur    = (int*)   (ws + 3 * MB + 320 * KB);  // 66 ints
    int*    perm    = (int*)   (ws + 4 * MB);             // 400 KB
    int*    iperm   = (int*)   (ws + 5 * MB);             // 400 KB
    int*    rowptr2 = (int*)   (ws + 6 * MB);             // 400 KB
    ushort* degS    = (ushort*)(ws + 7 * MB);             // 200 KB
    uint*   rec     = (uint*)  (ws + 8 * MB);             // 6.4 MB
    uint*   hbase   = (uint*)  (ws + 20 * MB);            // 10 x 12.8 MB
    const size_t HBYTES = (size_t)NG * NN * 8 * 4;        // 12.8 MB per h buffer
    uint*   tmp     = (uint*)  (ws + 20 * MB + 9 * HBYTES); // overlaps hbase[9] (dead until t=9)
    uint*   xq      = (uint*)  d_out;                     // 12.8 MB; dead by k_sum10

    (void)hipMemsetAsync(dcnt, 0, (NDC + 1) * sizeof(int), stream);

    k_hist   <<<PBLK, 256, 0, stream>>>(dst, histAll);
    k_colscan<<<NB, 256, 0, stream>>>(histAll, bcnt);
    k_scanb  <<<1, 512, 0, stream>>>(bcnt, bbase);
    k_partA2 <<<PBLK, 256, 0, stream>>>(src, dst, histAll, bbase, tmp);
    k_partB1 <<<NB, 256, 0, stream>>>(tmp, bbase, dinv, deg);
    k_dhist  <<<(NN + 255) / 256, 256, 0, stream>>>(deg, dcnt);
    k_dscan  <<<1, 128, 0, stream>>>(dcnt, dbase, ebase, dcur);
    k_dassign<<<(NN + 255) / 256, 256, 0, stream>>>(deg, dbase, ebase, dcur,
                                                    perm, iperm, rowptr2, degS);
    k_partB2 <<<NB, 256, 0, stream>>>(tmp, bbase, dinv, iperm, rowptr2, rec);
    k_xq     <<<(NN * NG + 255) / 256, 256, 0, stream>>>(x, perm, xq);

    const int propBlocks = NG * (NN / 16);     // 25000; group = blockIdx&3
    const uint* hcur = xq;
    for (int t = 0; t < STEPS; ++t) {
        uint* hn = (uint*)((char*)hbase + (size_t)t * HBYTES);
        k_prop<<<propBlocks, 256, 0, stream>>>(rowptr2, degS, rec, hcur, hn);
        hcur = hn;
    }

    k_sum10<<<(NN * NG + 255) / 256, 256, 0, stream>>>(hbase, x, perm, out);
}

// Round 15
// 750.546 us; speedup vs baseline: 2.7469x; 1.7563x over previous
//
#include <hip/hip_runtime.h>
#include <hip/hip_fp16.h>

#define NN 100000
#define NE 1600000
#define CH 64
#define STEPS 10
#define ALPHA 0.1f
#define NG 4                 // channel groups; group g -> XCDs {g, g+4}
#define GCH 16               // channels per group; row = 32 B

#define BW 256                       // nodes per bucket
#define NB ((NN + BW - 1) / BW)      // 391 buckets
#define PBLK 256                     // partition blocks
#define PCHUNK (NE / PBLK)           // 6250 edges per partition block
#define NDC 65                       // degree classes 0..64 (64 = clamp)

typedef unsigned int uint;
typedef unsigned short ushort;
typedef unsigned long long ull;

// pack two f32 into bf16x2 word, RNE (low half = first arg)
__device__ inline uint pack_bf16x2(float x, float y) {
    uint ux = __float_as_uint(x);
    ux += 0x7FFFu + ((ux >> 16) & 1u);
    uint uy = __float_as_uint(y);
    uy += 0x7FFFu + ((uy >> 16) & 1u);
    return (ux >> 16) | (uy & 0xFFFF0000u);
}

// ---- phase 1: per-block LDS bucket histogram -> dense histAll write ----
__global__ __launch_bounds__(256) void
k_hist(const int* __restrict__ dst, int* __restrict__ histAll) {
    __shared__ int hist[NB];
    int tid = threadIdx.x;
    for (int i = tid; i < NB; i += 256) hist[i] = 0;
    __syncthreads();
    int s0 = blockIdx.x * PCHUNK;
    for (int i = s0 + tid; i < s0 + PCHUNK; i += 256)
        atomicAdd(&hist[dst[i] >> 8], 1);
    __syncthreads();
    for (int b = tid; b < NB; b += 256)
        histAll[blockIdx.x * NB + b] = hist[b];
}

// ---- phase 2a: per-bucket scan over blocks ----
__global__ __launch_bounds__(256) void
k_colscan(int* __restrict__ histAll, int* __restrict__ bcnt) {
    __shared__ int lds[256];
    int b = blockIdx.x, tid = threadIdx.x;
    int v = histAll[tid * NB + b];
    lds[tid] = v;
    __syncthreads();
    for (int off = 1; off < 256; off <<= 1) {
        int t = (tid >= off) ? lds[tid - off] : 0;
        __syncthreads();
        lds[tid] += t;
        __syncthreads();
    }
    histAll[tid * NB + b] = lds[tid] - v;
    if (tid == 255) bcnt[b] = lds[255];
}

// ---- phase 2b: exclusive scan of 391 bucket sums ----
__global__ void k_scanb(const int* __restrict__ bcnt, int* __restrict__ bbase) {
    __shared__ int lds[512];
    int tid = threadIdx.x;
    int v = (tid < NB) ? bcnt[tid] : 0;
    lds[tid] = v;
    __syncthreads();
    for (int off = 1; off < 512; off <<= 1) {
        int t = (tid >= off) ? lds[tid - off] : 0;
        __syncthreads();
        lds[tid] += t;
        __syncthreads();
    }
    if (tid < NB) bbase[tid] = lds[tid] - v;
    if (tid == 0) bbase[NB] = NE;
}

// ---- phase 3: scatter 4B (src | dl<<17) into reserved dense runs ----
__global__ __launch_bounds__(256) void
k_partA2(const int* __restrict__ src, const int* __restrict__ dst,
         const int* __restrict__ histAll, const int* __restrict__ bbase,
         uint* __restrict__ tmp) {
    __shared__ int gb[NB];
    __shared__ int lcur[NB];
    int tid = threadIdx.x;
    for (int b = tid; b < NB; b += 256) {
        gb[b] = bbase[b] + histAll[blockIdx.x * NB + b];
        lcur[b] = 0;
    }
    __syncthreads();
    int s0 = blockIdx.x * PCHUNK;
    for (int i = s0 + tid; i < s0 + PCHUNK; i += 256) {
        int d = dst[i];
        int b = d >> 8;
        int r = atomicAdd(&lcur[b], 1);
        tmp[gb[b] + r] = (uint)src[i] | ((uint)(d & 255) << 17);
    }
}

// ---- phase 4: per-bucket degree histogram -> dinv + deg ----
__global__ __launch_bounds__(256) void
k_partB1(const uint* __restrict__ tmp, const int* __restrict__ bbase,
         float* __restrict__ dinv, int* __restrict__ deg) {
    __shared__ int hist[256];
    int b = blockIdx.x, tid = threadIdx.x;
    int nb0 = b * BW;
    int nodes = (NN - nb0 < BW) ? (NN - nb0) : BW;
    int base = bbase[b];
    int m = bbase[b + 1] - base;
    hist[tid] = 0;
    __syncthreads();
    for (int i = tid; i < m; i += 256)
        atomicAdd(&hist[(tmp[base + i] >> 17) & 255], 1);
    __syncthreads();
    if (tid < nodes) {
        int v = hist[tid];
        deg[nb0 + tid] = v;
        dinv[nb0 + tid] = rsqrtf(fmaxf((float)v, 1.0f));
    }
}

// ---- degree-class histogram, LDS-aggregated (65-counter contention fix) ----
__global__ __launch_bounds__(256) void
k_dhist(const int* __restrict__ deg, int* __restrict__ dcnt) {
    __shared__ int lh[NDC];
    int tid = threadIdx.x;
    if (tid < NDC) lh[tid] = 0;
    __syncthreads();
    int i = blockIdx.x * 256 + tid;
    if (i < NN) atomicAdd(&lh[min(deg[i], 64)], 1);
    __syncthreads();
    if (tid < NDC && lh[tid] > 0) atomicAdd(&dcnt[tid], lh[tid]);
}

// ---- scan degree classes: dbase (node base), ebase (edge base), cursors ----
__global__ void k_dscan(const int* __restrict__ dcnt, int* __restrict__ dbase,
                        int* __restrict__ ebase, int* __restrict__ dcur) {
    __shared__ int lc[128], le[128];
    int tid = threadIdx.x;
    int c = (tid < NDC) ? dcnt[tid] : 0;
    lc[tid] = c;
    le[tid] = c * tid;
    __syncthreads();
    for (int off = 1; off < 128; off <<= 1) {
        int tc = (tid >= off) ? lc[tid - off] : 0;
        int te = (tid >= off) ? le[tid - off] : 0;
        __syncthreads();
        lc[tid] += tc; le[tid] += te;
        __syncthreads();
    }
    if (tid < NDC) {
        int db = lc[tid] - c;
        dbase[tid] = db;
        ebase[tid] = le[tid] - c * tid;
        dcur[tid] = db;
        if (tid == NDC - 1) dcur[NDC] = le[tid] - c * tid;  // class-64 edge allocator
    }
}

// ---- assign permuted ids, LDS-aggregated allocation; rowptr2 closed form ----
__global__ __launch_bounds__(256) void
k_dassign(const int* __restrict__ deg, const int* __restrict__ dbase,
          const int* __restrict__ ebase, int* __restrict__ dcur,
          int* __restrict__ perm, int* __restrict__ iperm,
          int* __restrict__ rowptr2, ushort* __restrict__ degS) {
    __shared__ int lh[NDC];
    __shared__ int lb[NDC];
    int tid = threadIdx.x;
    if (tid < NDC) lh[tid] = 0;
    __syncthreads();
    int i = blockIdx.x * 256 + tid;
    bool act = i < NN;
    int v = 0, d = 0, myofs = 0;
    if (act) {
        v = deg[i];
        d = min(v, 64);
        myofs = atomicAdd(&lh[d], 1);      // LDS atomic: rank within (block, class)
    }
    __syncthreads();
    if (tid < NDC && lh[tid] > 0) lb[tid] = atomicAdd(&dcur[tid], lh[tid]);
    __syncthreads();
    if (act) {
        int nid = lb[d] + myofs;
        perm[nid] = i;
        iperm[i] = nid;
        int rp;
        if (d < 64) rp = ebase[d] + (nid - dbase[d]) * d;
        else        rp = atomicAdd(&dcur[NDC], v);
        rowptr2[nid] = rp;
        degS[nid] = (ushort)v;
    }
}

// ---- phase 5: emit 4B recs (permuted src | f16w>>1 << 17) at permuted CSR pos ----
__global__ __launch_bounds__(256) void
k_partB2(const uint* __restrict__ tmp, const int* __restrict__ bbase,
         const float* __restrict__ dinv, const int* __restrict__ iperm,
         const int* __restrict__ rowptr2, uint* __restrict__ rec) {
    __shared__ int lcur[256];
    __shared__ int lrp[256];
    int b = blockIdx.x, tid = threadIdx.x;
    int nb0 = b * BW;
    int nodes = (NN - nb0 < BW) ? (NN - nb0) : BW;
    int base = bbase[b];
    int m = bbase[b + 1] - base;
    lcur[tid] = 0;
    if (tid < nodes) lrp[tid] = rowptr2[iperm[nb0 + tid]];
    __syncthreads();
    for (int i = tid; i < m; i += 256) {
        uint r = tmp[base + i];
        int dl = (r >> 17) & 255;
        int sv = (int)(r & 0x1FFFFu);
        float w = dinv[sv] * dinv[nb0 + dl];
        ushort hw = __half_as_ushort(__float2half_rn(w));
        int k = atomicAdd(&lcur[dl], 1);
        rec[lrp[dl] + k] = (uint)iperm[sv] | ((uint)(hw >> 1) << 17);
    }
}

// ---- pack x into grouped/permuted bf16 layout [g][newid][32B] ----
__global__ __launch_bounds__(256) void
k_xq(const float* __restrict__ x, const int* __restrict__ perm, uint* __restrict__ xq) {
    int t = blockIdx.x * 256 + threadIdx.x;
    if (t >= NN * NG) return;
    int newid = t >> 2, g = t & 3;
    int orig = perm[newid];
    const float4* xr = (const float4*)(x + (size_t)orig * CH + g * GCH);
    float4 v0 = xr[0], v1 = xr[1], v2 = xr[2], v3 = xr[3];
    uint4* dp = (uint4*)(xq + ((size_t)g * NN + newid) * 8);
    dp[0] = make_uint4(pack_bf16x2(v0.x, v0.y), pack_bf16x2(v0.z, v0.w),
                       pack_bf16x2(v1.x, v1.y), pack_bf16x2(v1.z, v1.w));
    dp[1] = make_uint4(pack_bf16x2(v2.x, v2.y), pack_bf16x2(v2.z, v2.w),
                       pack_bf16x2(v3.x, v3.y), pack_bf16x2(v3.z, v3.w));
}

// ---- propagation: group g = blockIdx&3 (XCD-resident 3.2MB slice).
//      Wave = 4 equal-degree nodes x 4 edge-slots x 4 ch-lanes.
//      Straight-line batches: 4 trips always (16 edges/node) + 2 predicated
//      (<=24) + rare tail. 4-6 gathers in flight per wave. ----
__global__ __launch_bounds__(256) void
k_prop(const int* __restrict__ rowptr2, const ushort* __restrict__ degS,
       const uint* __restrict__ rec, const uint* __restrict__ hsrc,
       uint* __restrict__ hdst) {
    int g     = blockIdx.x & 3;
    int chunk = blockIdx.x >> 2;
    int lane  = threadIdx.x & 63;
    int slot  = (lane >> 2) & 3;         // edge slot [0,4)
    int c     = lane & 3;                // uint2 slot (4 ch) [0,4)
    int node  = chunk * 16 + (threadIdx.x >> 6) * 4 + (lane >> 4);   // newid
    int start = rowptr2[node];
    int d     = degS[node];
    int end   = start + d;
    int safe  = start < NE ? start : NE - 1;
    const uint2* __restrict__ hg = (const uint2*)hsrc + (size_t)g * (NN * 4);

    float a0 = 0.f, a1 = 0.f, a2 = 0.f, a3 = 0.f;

    #define FMA4(HV, WT)                                                \
        a0 = fmaf(__uint_as_float((HV).x << 16),         (WT), a0);     \
        a1 = fmaf(__uint_as_float((HV).x & 0xFFFF0000u), (WT), a1);     \
        a2 = fmaf(__uint_as_float((HV).y << 16),         (WT), a2);     \
        a3 = fmaf(__uint_as_float((HV).y & 0xFFFF0000u), (WT), a3);

    // batch 1: edges [start, start+16) — always (deg<=16: 57% of nodes)
    {
        uint r[4];
        #pragma unroll
        for (int j = 0; j < 4; ++j) {
            int ix = start + slot + 4 * j;
            r[j] = __builtin_nontemporal_load(rec + (ix < end ? ix : safe));
        }
        uint2 hv[4];
        #pragma unroll
        for (int j = 0; j < 4; ++j)
            hv[j] = hg[(size_t)(r[j] & 0x1FFFFu) * 4 + c];
        #pragma unroll
        for (int j = 0; j < 4; ++j) {
            int ix = start + slot + 4 * j;
            float wt = (ix < end)
                ? __half2float(__ushort_as_half((ushort)((r[j] >> 17) << 1))) : 0.0f;
            FMA4(hv[j], wt);
        }
    }
    // batch 2: edges [start+16, start+24) if d > 16 (covers <=24, ~98%)
    if (d > 16) {
        uint r[2];
        #pragma unroll
        for (int j = 0; j < 2; ++j) {
            int ix = start + 16 + slot + 4 * j;
            r[j] = __builtin_nontemporal_load(rec + (ix < end ? ix : safe));
        }
        uint2 hv[2];
        #pragma unroll
        for (int j = 0; j < 2; ++j)
            hv[j] = hg[(size_t)(r[j] & 0x1FFFFu) * 4 + c];
        #pragma unroll
        for (int j = 0; j < 2; ++j) {
            int ix = start + 16 + slot + 4 * j;
            float wt = (ix < end)
                ? __half2float(__ushort_as_half((ushort)((r[j] >> 17) << 1))) : 0.0f;
            FMA4(hv[j], wt);
        }
    }
    // rare tail: d > 24 (wave-uniform degree => coherent branching)
    for (int p = start + 24 + slot; p < end; p += 4) {
        uint r = rec[p];
        uint2 hv = hg[(size_t)(r & 0x1FFFFu) * 4 + c];
        float wt = __half2float(__ushort_as_half((ushort)((r >> 17) << 1)));
        FMA4(hv, wt);
    }
    #undef FMA4

    a0 += __shfl_xor(a0, 4); a1 += __shfl_xor(a1, 4);
    a2 += __shfl_xor(a2, 4); a3 += __shfl_xor(a3, 4);
    a0 += __shfl_xor(a0, 8); a1 += __shfl_xor(a1, 8);
    a2 += __shfl_xor(a2, 8); a3 += __shfl_xor(a3, 8);
    if (slot == 0) {
        ull* hd = (ull*)((uint2*)hdst + (size_t)g * (NN * 4));
        ull pack = (ull)pack_bf16x2(a0, a1) | ((ull)pack_bf16x2(a2, a3) << 32);
        __builtin_nontemporal_store(pack, &hd[(size_t)node * 4 + c]);
    }
}

// ---- final: out[perm[newid]] = alpha*x + (1-alpha)/STEPS * sum_t h_t ----
__global__ __launch_bounds__(256) void
k_sum10(const uint* __restrict__ hbase, const float* __restrict__ x,
        const int* __restrict__ perm, float* __restrict__ out) {
    int t = blockIdx.x * 256 + threadIdx.x;
    if (t >= NN * NG) return;
    int newid = t >> 2, g = t & 3;
    float s[16];
    #pragma unroll
    for (int j = 0; j < 16; ++j) s[j] = 0.f;
    #pragma unroll
    for (int st = 0; st < STEPS; ++st) {
        const uint4* b = (const uint4*)(hbase + (size_t)st * ((size_t)NG * NN * 8));
        uint4 v0 = b[((size_t)g * NN + newid) * 2];
        uint4 v1 = b[((size_t)g * NN + newid) * 2 + 1];
        s[0]  += __uint_as_float(v0.x << 16); s[1]  += __uint_as_float(v0.x & 0xFFFF0000u);
        s[2]  += __uint_as_float(v0.y << 16); s[3]  += __uint_as_float(v0.y & 0xFFFF0000u);
        s[4]  += __uint_as_float(v0.z << 16); s[5]  += __uint_as_float(v0.z & 0xFFFF0000u);
        s[6]  += __uint_as_float(v0.w << 16); s[7]  += __uint_as_float(v0.w & 0xFFFF0000u);
        s[8]  += __uint_as_float(v1.x << 16); s[9]  += __uint_as_float(v1.x & 0xFFFF0000u);
        s[10] += __uint_as_float(v1.y << 16); s[11] += __uint_as_float(v1.y & 0xFFFF0000u);
        s[12] += __uint_as_float(v1.z << 16); s[13] += __uint_as_float(v1.z & 0xFFFF0000u);
        s[14] += __uint_as_float(v1.w << 16); s[15] += __uint_as_float(v1.w & 0xFFFF0000u);
    }
    int orig = perm[newid];
    const float4* xr = (const float4*)(x + (size_t)orig * CH + g * GCH);
    float4* orow = (float4*)(out + (size_t)orig * CH + g * GCH);
    const float k = (1.0f - ALPHA) * (1.0f / STEPS);
    #pragma unroll
    for (int q = 0; q < 4; ++q) {
        float4 xv = xr[q];
        float4 r;
        r.x = ALPHA * xv.x + k * s[q * 4 + 0];
        r.y = ALPHA * xv.y + k * s[q * 4 + 1];
        r.z = ALPHA * xv.z + k * s[q * 4 + 2];
        r.w = ALPHA * xv.w + k * s[q * 4 + 3];
        orow[q] = r;
    }
}

extern "C" void kernel_launch(void* const* d_in, const int* in_sizes, int n_in,
                              void* d_out, int out_size, void* d_ws, size_t ws_size,
                              hipStream_t stream) {
    const float* x  = (const float*)d_in[0];
    const int*   ei = (const int*)d_in[1];     // [2, NE]: row0=src, row1=dst
    const int*   src = ei;
    const int*   dst = ei + NE;
    float* out = (float*)d_out;

    char* ws = (char*)d_ws;
    const size_t MB = 1024 * 1024;
    const size_t KB = 1024;
    int*    histAll = (int*)   (ws);                      // ~400 KB
    float*  dinv    = (float*) (ws + 1 * MB);             // 400 KB
    int*    deg     = (int*)   (ws + 2 * MB);             // 400 KB
    int*    bcnt    = (int*)   (ws + 3 * MB);             // tiny
    int*    bbase   = (int*)   (ws + 3 * MB + 64 * KB);   // tiny (+1)
    int*    dcnt    = (int*)   (ws + 3 * MB + 128 * KB);  // 65 ints
    int*    dbase   = (int*)   (ws + 3 * MB + 192 * KB);  // 65 ints
    int*    ebase   = (int*)   (ws + 3 * MB + 256 * KB);  // 65 ints
    int*    dcur    = (int*)   (ws + 3 * MB + 320 * KB);  // 66 ints
    int*    perm    = (int*)   (ws + 4 * MB);             // 400 KB
    int*    iperm   = (int*)   (ws + 5 * MB);             // 400 KB
    int*    rowptr2 = (int*)   (ws + 6 * MB);             // 400 KB
    ushort* degS    = (ushort*)(ws + 7 * MB);             // 200 KB
    uint*   rec     = (uint*)  (ws + 8 * MB);             // 6.4 MB
    uint*   hbase   = (uint*)  (ws + 20 * MB);            // 10 x 12.8 MB
    const size_t HBYTES = (size_t)NG * NN * 8 * 4;        // 12.8 MB per h buffer
    uint*   tmp     = (uint*)  (ws + 20 * MB + 9 * HBYTES); // overlaps hbase[9] (dead until t=9)
    uint*   xq      = (uint*)  d_out;                     // 12.8 MB; dead by k_sum10

    (void)hipMemsetAsync(dcnt, 0, (NDC + 1) * sizeof(int), stream);

    k_hist   <<<PBLK, 256, 0, stream>>>(dst, histAll);
    k_colscan<<<NB, 256, 0, stream>>>(histAll, bcnt);
    k_scanb  <<<1, 512, 0, stream>>>(bcnt, bbase);
    k_partA2 <<<PBLK, 256, 0, stream>>>(src, dst, histAll, bbase, tmp);
    k_partB1 <<<NB, 256, 0, stream>>>(tmp, bbase, dinv, deg);
    k_dhist  <<<(NN + 255) / 256, 256, 0, stream>>>(deg, dcnt);
    k_dscan  <<<1, 128, 0, stream>>>(dcnt, dbase, ebase, dcur);
    k_dassign<<<(NN + 255) / 256, 256, 0, stream>>>(deg, dbase, ebase, dcur,
                                                    perm, iperm, rowptr2, degS);
    k_partB2 <<<NB, 256, 0, stream>>>(tmp, bbase, dinv, iperm, rowptr2, rec);
    k_xq     <<<(NN * NG + 255) / 256, 256, 0, stream>>>(x, perm, xq);

    const int propBlocks = NG * (NN / 16);     // 25000; group = blockIdx&3
    const uint* hcur = xq;
    for (int t = 0; t < STEPS; ++t) {
        uint* hn = (uint*)((char*)hbase + (size_t)t * HBYTES);
        k_prop<<<propBlocks, 256, 0, stream>>>(rowptr2, degS, rec, hcur, hn);
        hcur = hn;
    }

    k_sum10<<<(NN * NG + 255) / 256, 256, 0, stream>>>(hbase, x, perm, out);
}

// Round 16
// 442.876 us; speedup vs baseline: 4.6552x; 1.6947x over previous
//
#include <hip/hip_runtime.h>
#include <hip/hip_fp16.h>

#define NN 100000
#define NE 1600000
#define CH 64
#define STEPS 10
#define ALPHA 0.1f

#define BW 256                       // nodes per bucket
#define NB ((NN + BW - 1) / BW)      // 391 buckets
#define PBLK 256                     // partition blocks
#define PCHUNK (NE / PBLK)           // 6250 edges per partition block

typedef unsigned int uint;
typedef unsigned short ushort;
typedef unsigned long long ull;

// pack two f32 into bf16x2 word, RNE (low half = first arg)
__device__ inline uint pack_bf16x2(float x, float y) {
    uint ux = __float_as_uint(x);
    ux += 0x7FFFu + ((ux >> 16) & 1u);
    uint uy = __float_as_uint(y);
    uy += 0x7FFFu + ((uy >> 16) & 1u);
    return (ux >> 16) | (uy & 0xFFFF0000u);
}

// ---- phase 1: per-block LDS bucket histogram -> dense histAll write ----
__global__ __launch_bounds__(256) void
k_hist(const int* __restrict__ dst, int* __restrict__ histAll) {
    __shared__ int hist[NB];
    int tid = threadIdx.x;
    for (int i = tid; i < NB; i += 256) hist[i] = 0;
    __syncthreads();
    int s0 = blockIdx.x * PCHUNK;
    for (int i = s0 + tid; i < s0 + PCHUNK; i += 256)
        atomicAdd(&hist[dst[i] >> 8], 1);
    __syncthreads();
    for (int b = tid; b < NB; b += 256)
        histAll[blockIdx.x * NB + b] = hist[b];
}

// ---- phase 2a: per-bucket scan over blocks ----
__global__ __launch_bounds__(256) void
k_colscan(int* __restrict__ histAll, int* __restrict__ bcnt) {
    __shared__ int lds[256];
    int b = blockIdx.x, tid = threadIdx.x;
    int v = histAll[tid * NB + b];
    lds[tid] = v;
    __syncthreads();
    for (int off = 1; off < 256; off <<= 1) {
        int t = (tid >= off) ? lds[tid - off] : 0;
        __syncthreads();
        lds[tid] += t;
        __syncthreads();
    }
    histAll[tid * NB + b] = lds[tid] - v;
    if (tid == 255) bcnt[b] = lds[255];
}

// ---- phase 2b: exclusive scan of 391 bucket sums ----
__global__ void k_scanb(const int* __restrict__ bcnt, int* __restrict__ bbase) {
    __shared__ int lds[512];
    int tid = threadIdx.x;
    int v = (tid < NB) ? bcnt[tid] : 0;
    lds[tid] = v;
    __syncthreads();
    for (int off = 1; off < 512; off <<= 1) {
        int t = (tid >= off) ? lds[tid - off] : 0;
        __syncthreads();
        lds[tid] += t;
        __syncthreads();
    }
    if (tid < NB) bbase[tid] = lds[tid] - v;
    if (tid == 0) bbase[NB] = NE;
}

// ---- phase 3: scatter 4B (src | dl<<17) into reserved dense runs ----
__global__ __launch_bounds__(256) void
k_partA2(const int* __restrict__ src, const int* __restrict__ dst,
         const int* __restrict__ histAll, const int* __restrict__ bbase,
         uint* __restrict__ tmp) {
    __shared__ int gb[NB];
    __shared__ int lcur[NB];
    int tid = threadIdx.x;
    for (int b = tid; b < NB; b += 256) {
        gb[b] = bbase[b] + histAll[blockIdx.x * NB + b];
        lcur[b] = 0;
    }
    __syncthreads();
    int s0 = blockIdx.x * PCHUNK;
    for (int i = s0 + tid; i < s0 + PCHUNK; i += 256) {
        int d = dst[i];
        int b = d >> 8;
        int r = atomicAdd(&lcur[b], 1);
        tmp[gb[b] + r] = (uint)src[i] | ((uint)(d & 255) << 17);
    }
}

// ---- phase 4: per-bucket degree histogram -> dinv + rowptr ----
__global__ __launch_bounds__(256) void
k_partB1(const uint* __restrict__ tmp, const int* __restrict__ bbase,
         float* __restrict__ dinv, int* __restrict__ rowptr) {
    __shared__ int hist[256];
    __shared__ int lds[256];
    int b = blockIdx.x, tid = threadIdx.x;
    int nb0 = b * BW;
    int nodes = (NN - nb0 < BW) ? (NN - nb0) : BW;
    int base = bbase[b];
    int m = bbase[b + 1] - base;
    hist[tid] = 0;
    __syncthreads();
    for (int i = tid; i < m; i += 256)
        atomicAdd(&hist[(tmp[base + i] >> 17) & 255], 1);
    __syncthreads();
    int v = hist[tid];
    lds[tid] = v;
    __syncthreads();
    for (int off = 1; off < 256; off <<= 1) {
        int t = (tid >= off) ? lds[tid - off] : 0;
        __syncthreads();
        lds[tid] += t;
        __syncthreads();
    }
    if (tid < nodes) {
        dinv[nb0 + tid] = rsqrtf(fmaxf((float)v, 1.0f));
        rowptr[nb0 + tid] = base + lds[tid] - v;
    }
    if (b == 0 && tid == 0) rowptr[NN] = NE;
}

// ---- phase 5: per-bucket sort-by-dst -> 4B rec = src | (f16(w)>>1)<<17 ----
__global__ __launch_bounds__(256) void
k_partB2(const uint* __restrict__ tmp, const int* __restrict__ bbase,
         const float* __restrict__ dinv, uint* __restrict__ rec) {
    __shared__ int hist[256];
    __shared__ int lds[256];
    __shared__ int lcur[256];
    int b = blockIdx.x, tid = threadIdx.x;
    int nb0 = b * BW;
    int base = bbase[b];
    int m = bbase[b + 1] - base;
    hist[tid] = 0;
    __syncthreads();
    for (int i = tid; i < m; i += 256)
        atomicAdd(&hist[(tmp[base + i] >> 17) & 255], 1);
    __syncthreads();
    int v = hist[tid];
    lds[tid] = v;
    __syncthreads();
    for (int off = 1; off < 256; off <<= 1) {
        int t = (tid >= off) ? lds[tid - off] : 0;
        __syncthreads();
        lds[tid] += t;
        __syncthreads();
    }
    lcur[tid] = lds[tid] - v;     // exclusive offset within bucket
    __syncthreads();
    for (int i = tid; i < m; i += 256) {
        uint r = tmp[base + i];
        int dl = (r >> 17) & 255;
        int sv = (int)(r & 0x1FFFFu);
        float w = dinv[sv] * dinv[nb0 + dl];
        ushort hw = __half_as_ushort(__float2half_rn(w));
        int p = atomicAdd(&lcur[dl], 1);
        rec[base + p] = (uint)sv | ((uint)(hw >> 1) << 17);
    }
}

// ---- pack x (f32 [node][64]) -> xq (bf16 [node][64], 128B rows) ----
__global__ __launch_bounds__(256) void
k_xq(const float* __restrict__ x, uint2* __restrict__ xq) {
    int t = blockIdx.x * 256 + threadIdx.x;      // [0, NN*16)
    if (t >= NN * 16) return;
    float4 v = ((const float4*)x)[t];
    xq[t] = make_uint2(pack_bf16x2(v.x, v.y), pack_bf16x2(v.z, v.w));
}

// ---- propagation (round-11 structure, 4B records): one wave per node;
//      q=lane>>4 owns edge slot, cl=lane&15 owns 4 channels (uint2 bf16).
//      Batch 16 always + 8 predicated (uniform branch) + rare loop. ----
__global__ __launch_bounds__(256) void
k_prop(const int* __restrict__ rowptr, const uint* __restrict__ rec,
       const uint2* __restrict__ h, uint2* __restrict__ hn) {
    int wid  = (int)((blockIdx.x * (long long)blockDim.x + threadIdx.x) >> 6);
    int lane = threadIdx.x & 63;
    if (wid >= NN) return;
    int q  = lane >> 4;
    int cl = lane & 15;
    int start = rowptr[wid];
    int end   = rowptr[wid + 1];
    int safe  = start < NE ? start : NE - 1;

    float a0 = 0.f, a1 = 0.f, a2 = 0.f, a3 = 0.f;

    #define GATHER_FMA(RV, ACTIVE)                                               \
        {                                                                        \
            int   s_ = (int)((RV) & 0x1FFFFu);                                   \
            float wt = (ACTIVE)                                                  \
                ? __half2float(__ushort_as_half((ushort)(((RV) >> 17) << 1)))    \
                : 0.0f;                                                          \
            uint2 hv = h[(long long)s_ * 16 + cl];                               \
            a0 = fmaf(__uint_as_float(hv.x << 16),        wt, a0);               \
            a1 = fmaf(__uint_as_float(hv.x & 0xFFFF0000u), wt, a1);              \
            a2 = fmaf(__uint_as_float(hv.y << 16),        wt, a2);               \
            a3 = fmaf(__uint_as_float(hv.y & 0xFFFF0000u), wt, a3);              \
        }

    {
        uint rv[4];
        #pragma unroll
        for (int j = 0; j < 4; ++j) {
            int ix = start + 4 * j + q;
            rv[j] = rec[ix < end ? ix : safe];
        }
        #pragma unroll
        for (int j = 0; j < 4; ++j) {
            int ix = start + 4 * j + q;
            GATHER_FMA(rv[j], ix < end);
        }
    }
    if (end > start + 16) {
        uint rv[2];
        #pragma unroll
        for (int j = 0; j < 2; ++j) {
            int ix = start + 16 + 4 * j + q;
            rv[j] = rec[ix < end ? ix : safe];
        }
        #pragma unroll
        for (int j = 0; j < 2; ++j) {
            int ix = start + 16 + 4 * j + q;
            GATHER_FMA(rv[j], ix < end);
        }
    }
    for (int p = start + 24; p < end; p += 4) {
        int ix = p + q;
        if (ix < end) {
            uint rv = rec[ix];
            GATHER_FMA(rv, true);
        }
    }
    #undef GATHER_FMA

    a0 += __shfl_xor(a0, 16); a1 += __shfl_xor(a1, 16);
    a2 += __shfl_xor(a2, 16); a3 += __shfl_xor(a3, 16);
    a0 += __shfl_xor(a0, 32); a1 += __shfl_xor(a1, 32);
    a2 += __shfl_xor(a2, 32); a3 += __shfl_xor(a3, 32);

    if (q == 0) {
        long long o = (long long)wid * 16 + cl;
        hn[o] = make_uint2(pack_bf16x2(a0, a1), pack_bf16x2(a2, a3));
    }
}

// ---- deferred combine: out = alpha*x + (1-alpha)/STEPS * sum_t h_t ----
__global__ void k_sum10(const uint2* __restrict__ hbase, const float* __restrict__ x,
                        float* __restrict__ out, int total) {
    int i = blockIdx.x * blockDim.x + threadIdx.x;
    if (i >= total) return;
    float s0 = 0.f, s1 = 0.f, s2 = 0.f, s3 = 0.f;
    #pragma unroll
    for (int t = 0; t < STEPS; ++t) {
        uint2 v = hbase[(size_t)t * (NN * 16) + i];
        s0 += __uint_as_float(v.x << 16);
        s1 += __uint_as_float(v.x & 0xFFFF0000u);
        s2 += __uint_as_float(v.y << 16);
        s3 += __uint_as_float(v.y & 0xFFFF0000u);
    }
    float4 xv = ((const float4*)x)[i];
    float4 r;
    r.x = ALPHA * xv.x + (1.0f - ALPHA) * (s0 * (1.0f / STEPS));
    r.y = ALPHA * xv.y + (1.0f - ALPHA) * (s1 * (1.0f / STEPS));
    r.z = ALPHA * xv.z + (1.0f - ALPHA) * (s2 * (1.0f / STEPS));
    r.w = ALPHA * xv.w + (1.0f - ALPHA) * (s3 * (1.0f / STEPS));
    ((float4*)out)[i] = r;
}

extern "C" void kernel_launch(void* const* d_in, const int* in_sizes, int n_in,
                              void* d_out, int out_size, void* d_ws, size_t ws_size,
                              hipStream_t stream) {
    const float* x  = (const float*)d_in[0];
    const int*   ei = (const int*)d_in[1];     // [2, NE]: row0=src, row1=dst
    const int*   src = ei;
    const int*   dst = ei + NE;
    float* out = (float*)d_out;

    char* ws = (char*)d_ws;
    const size_t MB = 1024 * 1024;
    const size_t KB = 1024;
    int*   histAll = (int*)  (ws);                     // ~400 KB
    float* dinv    = (float*)(ws + 1 * MB);            // 400 KB
    int*   rowptr  = (int*)  (ws + 2 * MB);            // 400 KB (+1)
    int*   bcnt    = (int*)  (ws + 3 * MB);            // tiny
    int*   bbase   = (int*)  (ws + 3 * MB + 64 * KB);  // tiny (+1)
    uint*  rec     = (uint*) (ws + 5 * MB);            // 6.4 MB (final CSR, 4B recs)
    uint2* hbase   = (uint2*)(ws + 20 * MB);           // 10 x 12.8 MB = 128 MB
    uint*  tmp     = (uint*) (ws + 20 * MB);           // 6.4 MB (dead before prop 0)
    uint2* xq      = (uint2*)d_out;                    // 12.8 MB; dead by k_sum10

    const size_t HBUF = (size_t)NN * 16;               // uint2 per h buffer

    k_hist   <<<PBLK, 256, 0, stream>>>(dst, histAll);
    k_colscan<<<NB, 256, 0, stream>>>(histAll, bcnt);
    k_scanb  <<<1, 512, 0, stream>>>(bcnt, bbase);
    k_partA2 <<<PBLK, 256, 0, stream>>>(src, dst, histAll, bbase, tmp);
    k_partB1 <<<NB, 256, 0, stream>>>(tmp, bbase, dinv, rowptr);
    k_partB2 <<<NB, 256, 0, stream>>>(tmp, bbase, dinv, rec);
    k_xq     <<<(NN * 16 + 255) / 256, 256, 0, stream>>>(x, xq);

    const int propBlocks = (NN * 64 + 255) / 256;      // one wave per node

    const uint2* hcur = xq;
    for (int t = 0; t < STEPS; ++t) {
        uint2* hn = hbase + (size_t)t * HBUF;
        k_prop<<<propBlocks, 256, 0, stream>>>(rowptr, rec, hcur, hn);
        hcur = hn;
    }

    const int total = NN * 16;
    k_sum10<<<(total + 255) / 256, 256, 0, stream>>>(hbase, x, out, total);
}